// Round 4
// baseline (286.528 us; speedup 1.0000x reference)
//
#include <hip/hip_runtime.h>

// EmbeddingCRF: feats = emb[sentence] @ W^T; CRF forward (LSE), gold score,
// Viterbi decode. Parallel-in-time via 12x12 semiring transfer matrices.
// R7: grid.sync ~31us each -> cooperative fusion abandoned; ordinary
// dispatches (~6us) are the cheap barrier. 6 dispatches, 244us.
// R8: 6 -> 4 dispatches. (a) fold1 merged INTO pass1: one block owns all 16
// chunks of a super (16 chunks x 16 cols = 256 thr, one semiring per block),
// drops chunk mats in LDS, folds in-block -> SMV/SMVT/SMF directly.
// __launch_bounds__(256,1) so the ~200-VGPR scan doesn't spill (R5 trap).
// (b) fold2+mid+expandA replaced by k_midS: direct 128-step serial vector
// scans over super matrices (shfl-broadcast + tree-max, ~60-100cyc/step);
// the scan emits all 128 SBV/SSFX vectors as it goes (what expandA did).
// Hyper level eliminated entirely.

#define LSEQ    32768
#define NTAGS   14
#define R       12
#define T_START 12
#define T_STOP  13
#define EMBD    300
#define CCH     2048  // chunks
#define SCH     16    // steps per chunk
#define NSUP    128   // supers (16 chunks each)

// ws layout (float offsets)
#define OFF_FEATS 0         // [L][12]
#define OFF_EXPF  393216    // [L][12]
#define OFF_FMAX  786432    // [L]
#define OFF_PF    819200    // [2048][n][p] LSE chunk mats (log domain)
#define OFF_PV    1114112   // [2048][n][p] max-plus chunk mats
#define OFF_PVC   1409024   // [2048][p][n] transposed
#define OFF_BV    1703936   // (unused; layout keeps regions stable)
#define OFF_SFX   1728512   // (unused)
#define OFF_GOLD  1753088   // (unused)
#define OFF_SMV   1753104   // [128][n][p]
#define OFF_SMVT  1771536   // [128][p][n]
#define OFF_SMF   1789968   // [128][n][p]
#define OFF_HMV   1808400   // (unused since R8; safe off-end prefetch target)
#define OFF_SBV   1811856   // [128][12]
#define OFF_SSFX  1813392   // [128][12]
#define OFF_GOLDP 1815120   // [2048] per-block gold partials

__device__ __forceinline__ void load12(const float* __restrict__ p, float* r) {
  const float4* p4 = (const float4*)p;
  float4 a = p4[0], b = p4[1], c = p4[2];
  r[0]=a.x; r[1]=a.y; r[2]=a.z; r[3]=a.w;
  r[4]=b.x; r[5]=b.y; r[6]=b.z; r[7]=b.w;
  r[8]=c.x; r[9]=c.y; r[10]=c.z; r[11]=c.w;
}

__device__ __forceinline__ void lds12(const float* p, float* r) {
  const float4* p4 = (const float4*)p;
  float4 a = p4[0], b = p4[1], c = p4[2];
  r[0]=a.x; r[1]=a.y; r[2]=a.z; r[3]=a.w;
  r[4]=b.x; r[5]=b.y; r[6]=b.z; r[7]=b.w;
  r[8]=c.x; r[9]=c.y; r[10]=c.z; r[11]=c.w;
}

__device__ __forceinline__ float tmax12(const float* t) {
  float a = fmaxf(fmaxf(t[0], t[1]), fmaxf(t[2], t[3]));
  float b = fmaxf(fmaxf(t[4], t[5]), fmaxf(t[6], t[7]));
  float c = fmaxf(fmaxf(t[8], t[9]), fmaxf(t[10], t[11]));
  return fmaxf(fmaxf(a, b), c);
}

// ---------------- K1: feats + expfeat + featmax + gold partials -------------
__global__ __launch_bounds__(256) void k_feats(
    const int* __restrict__ sentence, const int* __restrict__ tags,
    const float* __restrict__ emb, const float* __restrict__ W,
    const float* __restrict__ trans, float* __restrict__ ws)
{
  __shared__ float Wl[NTAGS * EMBD];
  __shared__ float gacc;
  for (int i = threadIdx.x; i < NTAGS * EMBD; i += 256) Wl[i] = W[i];
  if (threadIdx.x == 0) gacc = 0.f;
  __syncthreads();

  int grp = threadIdx.x >> 4;
  int g   = threadIdx.x & 15;
  int pos = blockIdx.x * 16 + grp;
  int row = sentence[pos];

  float acc = 0.f;
  if (g < R) {
    const float4* e4 = (const float4*)(emb + (size_t)row * EMBD);
    const float4* w4 = (const float4*)(Wl + g * EMBD);
    #pragma unroll 5
    for (int i = 0; i < EMBD / 4; ++i) {
      float4 a = e4[i]; float4 b = w4[i];
      acc += a.x*b.x + a.y*b.y + a.z*b.z + a.w*b.w;
    }
  }
  float feat = (g < R) ? acc : -3.0e38f;
  float mx = feat;
  #pragma unroll
  for (int off = 1; off < 16; off <<= 1)
    mx = fmaxf(mx, __shfl_xor(mx, off, 16));

  if (g < R) {
    ws[OFF_FEATS + pos * 12 + g] = feat;
    ws[OFF_EXPF  + pos * 12 + g] = __expf(feat - mx);
  }
  if (g == 0) ws[OFF_FMAX + pos] = mx;

  int tg = tags[pos];
  if (g == tg) {
    int prev = (pos == 0) ? T_START : tags[pos - 1];
    float gc = feat + trans[tg * NTAGS + prev];
    if (pos == LSEQ - 1) gc += trans[T_STOP * NTAGS + tg];
    atomicAdd(&gacc, gc);
  }
  __syncthreads();
  if (threadIdx.x == 0) ws[OFF_GOLDP + blockIdx.x] = gacc;
}

// ---------------- K2: chunk transfer matrices + in-block fold1 --------------
// grid 256 = 128 supers x 2 semirings (sem = bid>>7: 0 LSE, 1 viterbi).
// block 256 thr = 16 chunks x 16 cols. Phase A: per-thread 16-step chunk
// scan (exact k_pass1 math); chunk mats -> global (PF / PV+PVC) AND LDS.
// Phase B: threads 0..143 fold the 16 LDS mats -> super mat (SMF / SMV+SMVT).
// __launch_bounds__(256,1): allow ~200 VGPR, 1 wave/SIMD — no spill (R5 trap).
__global__ __launch_bounds__(256, 1) void k_pass1f(
    const float* __restrict__ trans, float* __restrict__ ws)
{
  __shared__ float Msh[16 * 144];   // 9.2 KB
  __shared__ float Vl[144];

  int tid = threadIdx.x;
  int sem = blockIdx.x >> 7;
  int s   = blockIdx.x & 127;
  int q = tid >> 4;
  int p = tid & 15;
  int c = s * 16 + q;
  int t0 = (c == 0) ? 1 : c * SCH;
  int t1 = c * SCH + SCH;
  bool act = (p < R);

  float Treg[R][R];

  if (sem == 0) {
    // LSE semiring (prob domain with exponent rescaling)
    #pragma unroll
    for (int n = 0; n < R; ++n)
      #pragma unroll
      for (int m = 0; m < R; ++m)
        Treg[n][m] = __expf(trans[n * NTAGS + m]);

    float E[R];
    #pragma unroll
    for (int m = 0; m < R; ++m) E[m] = (m == p) ? 1.f : 0.f;
    int kacc = 0;
    float sfeat = 0.f;

    float ef[R];
    load12(ws + OFF_EXPF + t0 * 12, ef);
    float fm = ws[OFF_FMAX + t0];

    for (int t = t0; t < t1; ++t) {
      float efn[R];
      load12(ws + OFF_EXPF + (t + 1) * 12, efn);   // off-end lands in FMAX: safe
      float fmn = ws[OFF_FMAX + t + 1];            // off-end lands in PF: safe
      sfeat += fm;
      float NE[R];
      #pragma unroll
      for (int n = 0; n < R; ++n) {
        float sv = Treg[n][0] * E[0];
        #pragma unroll
        for (int m = 1; m < R; ++m) sv = fmaf(Treg[n][m], E[m], sv);
        NE[n] = sv * ef[n];
      }
      #pragma unroll
      for (int n = 0; n < R; ++n) E[n] = NE[n];
      if ((t & 7) == 7) {
        float mx = E[0];
        #pragma unroll
        for (int n = 1; n < R; ++n) mx = fmaxf(mx, E[n]);
        if (mx > 0.f) {
          int k = ((__float_as_int(mx) >> 23) & 0xFF) - 127;
          float sc = __int_as_float((127 - k) << 23);
          #pragma unroll
          for (int n = 0; n < R; ++n) E[n] *= sc;
          kacc += k;
        }
      }
      #pragma unroll
      for (int n = 0; n < R; ++n) ef[n] = efn[n];
      fm = fmn;
    }
    if (act) {
      float base = (float)kacc * 0.6931471805599453f + sfeat;
      #pragma unroll
      for (int n = 0; n < R; ++n) {
        float v = (E[n] > 0.f) ? (__logf(E[n]) + base) : -1.0e30f;
        ws[OFF_PF + c * 144 + n * 12 + p] = v;
        Msh[q * 144 + n * 12 + p] = v;
      }
    }
  } else {
    // max-plus semiring
    #pragma unroll
    for (int n = 0; n < R; ++n)
      #pragma unroll
      for (int m = 0; m < R; ++m)
        Treg[n][m] = trans[n * NTAGS + m];

    float V[R];
    #pragma unroll
    for (int m = 0; m < R; ++m) V[m] = (m == p) ? 0.f : -1.0e30f;

    float fr[R];
    load12(ws + OFF_FEATS + t0 * 12, fr);

    for (int t = t0; t < t1; ++t) {
      float frn[R];
      load12(ws + OFF_FEATS + (t + 1) * 12, frn);  // off-end lands in EXPF: safe
      float NV[R];
      #pragma unroll
      for (int n = 0; n < R; ++n) {
        float b = Treg[n][0] + V[0];
        #pragma unroll
        for (int m = 1; m < R; ++m) b = fmaxf(b, Treg[n][m] + V[m]);
        NV[n] = b + fr[n];
      }
      #pragma unroll
      for (int n = 0; n < R; ++n) { V[n] = NV[n]; fr[n] = frn[n]; }
    }
    if (act) {
      #pragma unroll
      for (int n = 0; n < R; ++n) {
        ws[OFF_PV  + c * 144 + n * 12 + p] = V[n];
        ws[OFF_PVC + c * 144 + p * 12 + n] = V[n];
        Msh[q * 144 + n * 12 + p] = V[n];
      }
    }
  }
  __syncthreads();

  // Phase B: fold 16 chunk mats (LDS) -> super mat
  {
    int l = tid;
    bool fa = (l < 144);
    int fn = l / 12;
    int fp = l - fn * 12;
    float V = (fa && fn == fp) ? 0.f : -1.0e30f;

    for (int j = 0; j < 16; ++j) {
      if (fa) Vl[l] = V;
      __syncthreads();
      if (fa) {
        const float* M = Msh + j * 144 + fn * 12;
        if (sem == 1) {
          float best = -3.0e38f;
          #pragma unroll
          for (int m = 0; m < R; ++m)
            best = fmaxf(best, M[m] + Vl[m * 12 + fp]);
          V = best;
        } else {
          float cand[R]; float mx = -3.0e38f;
          #pragma unroll
          for (int m = 0; m < R; ++m) {
            cand[m] = M[m] + Vl[m * 12 + fp];
            mx = fmaxf(mx, cand[m]);
          }
          float sum = 0.f;
          #pragma unroll
          for (int m = 0; m < R; ++m) sum += __expf(cand[m] - mx);
          V = mx + __logf(sum);
        }
      }
      __syncthreads();
    }
    if (fa) {
      if (sem == 1) {
        ws[OFF_SMV  + s * 144 + fn * 12 + fp] = V;
        ws[OFF_SMVT + s * 144 + fp * 12 + fn] = V;
      } else {
        ws[OFF_SMF + s * 144 + fn * 12 + fp] = V;
      }
    }
  }
}

// ---------------- K_midS: serial super-level scans + gold (1 block) ---------
// wave0: viterbi fwd over SMV, 128 steps, emits SBV[s] each step + out[1].
// wave1: viterbi suffix over SMVT, 128 steps, emits SSFX[s].
// wave2: LSE fwd over SMF, 128 steps -> lse. wave3: gold reduce.
// Vector lives one element/lane (lanes 0..11); broadcast via width-16 shfl,
// tree-max depth 4 — ~60-100 cyc/step serial chain, no LDS round-trip.
__global__ __launch_bounds__(256) void k_midS(
    const float* __restrict__ trans, float* __restrict__ ws,
    float* __restrict__ out)
{
  __shared__ float gold_sh, lse_sh;
  int tid  = threadIdx.x;
  int wid  = tid >> 6;
  int lane = tid & 63;
  int n = lane;
  bool act = (n < R);

  if (wid == 0) {
    // Viterbi forward: v = entry vector; SBV[s] = v before applying SMV[s]
    float v = act ? (trans[n * NTAGS + T_START] + ws[OFF_FEATS + n]) : -3.0e38f;
    float row[R], rown[R];
    if (act) load12(ws + OFF_SMV + n * 12, row);
    for (int s = 0; s < NSUP; ++s) {
      if (act) load12(ws + OFF_SMV + (s + 1) * 144 + n * 12, rown); // s=127 -> SMVT: safe
      if (act) ws[OFF_SBV + s * 12 + n] = v;
      float vb[R];
      #pragma unroll
      for (int m = 0; m < R; ++m) vb[m] = __shfl(v, m, 16);
      if (act) {
        float t[R];
        #pragma unroll
        for (int m = 0; m < R; ++m) t[m] = row[m] + vb[m];
        v = tmax12(t);
        #pragma unroll
        for (int m = 0; m < R; ++m) row[m] = rown[m];
      }
    }
    float t = act ? (v + trans[T_STOP * NTAGS + n]) : -3.0e38f;
    #pragma unroll
    for (int off = 1; off < 16; off <<= 1)
      t = fmaxf(t, __shfl_xor(t, off, 16));
    if (lane == 0) out[1] = t;
  } else if (wid == 1) {
    // Viterbi suffix: u = suffix at exit of super s; SSFX[s] = u
    float u = act ? trans[T_STOP * NTAGS + n] : -3.0e38f;
    if (act) ws[OFF_SSFX + (NSUP - 1) * 12 + n] = u;
    float row[R], rown[R];
    if (act) load12(ws + OFF_SMVT + (NSUP - 1) * 144 + n * 12, row);
    for (int s = NSUP - 1; s >= 1; --s) {
      if (act) load12(ws + OFF_SMVT + (s - 1) * 144 + n * 12, rown);
      float ub[R];
      #pragma unroll
      for (int m = 0; m < R; ++m) ub[m] = __shfl(u, m, 16);
      if (act) {
        float t[R];
        #pragma unroll
        for (int m = 0; m < R; ++m) t[m] = row[m] + ub[m];
        u = tmax12(t);
        ws[OFF_SSFX + (s - 1) * 12 + n] = u;
        #pragma unroll
        for (int m = 0; m < R; ++m) row[m] = rown[m];
      }
    }
  } else if (wid == 2) {
    // LSE forward
    float w = act ? (trans[n * NTAGS + T_START] + ws[OFF_FEATS + n]) : -3.0e38f;
    float row[R], rown[R];
    if (act) load12(ws + OFF_SMF + n * 12, row);
    for (int s = 0; s < NSUP; ++s) {
      if (act) load12(ws + OFF_SMF + (s + 1) * 144 + n * 12, rown); // s=127 -> HMV: safe
      float wb[R];
      #pragma unroll
      for (int m = 0; m < R; ++m) wb[m] = __shfl(w, m, 16);
      if (act) {
        float t[R];
        #pragma unroll
        for (int m = 0; m < R; ++m) t[m] = row[m] + wb[m];
        float mx = tmax12(t);
        float sum = 0.f;
        #pragma unroll
        for (int m = 0; m < R; ++m) sum += __expf(t[m] - mx);
        w = mx + __logf(sum);
        #pragma unroll
        for (int m = 0; m < R; ++m) row[m] = rown[m];
      }
    }
    float t = act ? (w + trans[T_STOP * NTAGS + n]) : -3.0e38f;
    float mx = t;
    #pragma unroll
    for (int off = 1; off < 16; off <<= 1)
      mx = fmaxf(mx, __shfl_xor(mx, off, 16));
    float e = act ? __expf(t - mx) : 0.f;
    #pragma unroll
    for (int off = 1; off < 16; off <<= 1)
      e += __shfl_xor(e, off, 16);
    if (lane == 0) lse_sh = mx + __logf(e);
  } else {
    // gold reduce over 2048 partials
    float sg = 0.f;
    for (int i = lane; i < CCH; i += 64) sg += ws[OFF_GOLDP + i];
    #pragma unroll
    for (int off = 1; off < 64; off <<= 1) sg += __shfl_xor(sg, off);
    if (lane == 0) gold_sh = sg;
  }
  __syncthreads();
  if (tid == 0) out[0] = lse_sh - gold_sh;
}

// ---------------- K_expBdec: per-super expandB scans + decode ---------------
// 128 blocks x 256 thr. Phase A: wave0 lanes 0-15 compute BV for the super's
// 16 chunks (LDS); wave1 lanes 0-15 compute SFX. Phase B: decode 16 chunks
// x 16 lanes. No BV/SFX global round-trip.
__global__ __launch_bounds__(256) void k_expBdec(
    const float* __restrict__ trans, const float* __restrict__ ws,
    float* __restrict__ out)
{
  __shared__ float bv_sh[SCH][12];
  __shared__ float sfx_sh[SCH][12];
  __shared__ float Vdec[SCH][16];
  __shared__ unsigned char bpd[SCH][SCH][16];

  int tid = threadIdx.x;
  int s   = blockIdx.x;

  if (tid < 16) {
    // dir0: BV scan over PV mats
    int g = tid; bool act = (g < R);
    float x = -3.0e38f;
    if (act) { x = ws[OFF_SBV + s * 12 + g]; bv_sh[0][g] = x; }
    float row[R], rown[R];
    if (act) load12(ws + OFF_PV + (s * 16) * 144 + g * 12, row);
    for (int j = 0; j < 15; ++j) {
      if (act) load12(ws + OFF_PV + (s * 16 + j + 1) * 144 + g * 12, rown);
      float v[R];
      lds12(bv_sh[j], v);
      if (act) {
        float nx = row[0] + v[0];
        #pragma unroll
        for (int m = 1; m < R; ++m) nx = fmaxf(nx, row[m] + v[m]);
        bv_sh[j + 1][g] = nx;
        #pragma unroll
        for (int m = 0; m < R; ++m) row[m] = rown[m];
      }
    }
  } else if (tid >= 64 && tid < 80) {
    // dir1: SFX scan over PVC mats
    int g = tid - 64; bool act = (g < R);
    float x = -3.0e38f;
    if (act) { x = ws[OFF_SSFX + s * 12 + g]; sfx_sh[SCH - 1][g] = x; }
    float row[R], rown[R];
    if (act) load12(ws + OFF_PVC + (s * 16 + 15) * 144 + g * 12, row);
    for (int j = 15; j >= 1; --j) {
      if (act) load12(ws + OFF_PVC + (s * 16 + j - 1) * 144 + g * 12, rown);
      float v[R];
      lds12(sfx_sh[j], v);
      if (act) {
        float nx = row[0] + v[0];
        #pragma unroll
        for (int m = 1; m < R; ++m) nx = fmaxf(nx, row[m] + v[m]);
        sfx_sh[j - 1][g] = nx;
        #pragma unroll
        for (int m = 0; m < R; ++m) row[m] = rown[m];
      }
    }
  }
  __syncthreads();

  // decode: 16 chunks x 16 lanes
  {
    int q = tid >> 4;
    int g = tid & 15;
    int c = s * 16 + q;
    int t0 = (c == 0) ? 1 : c * SCH;
    int t1 = c * SCH + SCH;
    bool act = (g < R);

    float treg[R];
    #pragma unroll
    for (int m = 0; m < R; ++m) treg[m] = act ? trans[g * NTAGS + m] : 0.f;

    float fv = act ? bv_sh[q][g] : -3.0e38f;
    Vdec[q][g] = fv;
    float fc = ws[OFF_FEATS + t0 * 12 + g];

    for (int t = t0; t < t1; ++t) {
      float fn = ws[OFF_FEATS + (t + 1) * 12 + g];   // off-end: EXPF, unused
      float v[R];
      lds12(Vdec[q], v);
      float best = -3.0e38f; int bi = 0;
      #pragma unroll
      for (int m = 0; m < R; ++m) {
        float cand = treg[m] + v[m];
        if (cand > best) { best = cand; bi = m; }
      }
      float nfv = best + fc;
      if (act) {
        bpd[q][t - t0][g] = (unsigned char)bi;
        Vdec[q][g] = nfv;
      }
      fc = fn;
    }

    Vdec[q][g] = act ? (Vdec[q][g] + sfx_sh[q][g]) : -3.0e38f;

    if (g == 0) {
      float best = Vdec[q][0]; int idx = 0;
      #pragma unroll
      for (int m = 1; m < R; ++m) {
        float v = Vdec[q][m];
        if (v > best) { best = v; idx = m; }
      }
      int cur = idx;
      int len = t1 - t0;
      out[2 + t0 + len - 1] = (float)cur;
      for (int tt = len - 1; tt >= 1; --tt) {
        cur = bpd[q][tt][cur];
        out[2 + t0 + tt - 1] = (float)cur;
      }
      if (c == 0) {
        cur = bpd[q][0][cur];
        out[2 + 0] = (float)cur;
      }
    }
  }
}

extern "C" void kernel_launch(void* const* d_in, const int* in_sizes, int n_in,
                              void* d_out, int out_size, void* d_ws, size_t ws_size,
                              hipStream_t stream) {
  (void)in_sizes; (void)n_in; (void)out_size; (void)ws_size;
  const int*   sentence = (const int*)d_in[0];
  const int*   tags     = (const int*)d_in[1];
  const float* emb      = (const float*)d_in[2];
  const float* W        = (const float*)d_in[3];
  const float* trans    = (const float*)d_in[4];
  float* ws  = (float*)d_ws;
  float* out = (float*)d_out;

  k_feats<<<LSEQ / 16, 256, 0, stream>>>(sentence, tags, emb, W, trans, ws);
  k_pass1f<<<NSUP * 2, 256, 0, stream>>>(trans, ws);
  k_midS<<<1, 256, 0, stream>>>(trans, ws, out);
  k_expBdec<<<NSUP, 256, 0, stream>>>(trans, ws, out);
}

// Round 5
// 264.265 us; speedup vs baseline: 1.0842x; 1.0842x over previous
//
#include <hip/hip_runtime.h>

// EmbeddingCRF: feats = emb[sentence] @ W^T; CRF forward (LSE), gold score,
// Viterbi decode. Parallel-in-time via 12x12 semiring transfer matrices.
// R7: grid.sync ~31us -> cooperative fusion abandoned; dispatches (~6us) are
// the cheap barrier. R8: 4 dispatches (fold1 inside pass1; hyper level
// replaced by direct 128-step scans) — but k_midS hit 78us: each scan step's
// 12x12-matrix load is a ~900cy remote-L2/HBM access (written by other XCDs)
// and 1-deep prefetch hides only ~100cy. R9: bulk-stage the scan inputs into
// LDS first (addresses are state-independent), then scan from LDS:
//   k_midS block 0: stage SMV+SMVT (147KB LDS), viterbi fwd + suffix scans;
//   k_midS block 1: stage SMF (72KB), LSE scan + gold reduce.
// Scan math identical to R8. Still 4 dispatches.

#define LSEQ    32768
#define NTAGS   14
#define R       12
#define T_START 12
#define T_STOP  13
#define EMBD    300
#define CCH     2048  // chunks
#define SCH     16    // steps per chunk
#define NSUP    128   // supers (16 chunks each)

// ws layout (float offsets)
#define OFF_FEATS 0         // [L][12]
#define OFF_EXPF  393216    // [L][12]
#define OFF_FMAX  786432    // [L]
#define OFF_PF    819200    // [2048][n][p] LSE chunk mats (log domain)
#define OFF_PV    1114112   // [2048][n][p] max-plus chunk mats
#define OFF_PVC   1409024   // [2048][p][n] transposed
#define OFF_SMV   1753104   // [128][n][p]
#define OFF_SMVT  1771536   // [128][p][n]
#define OFF_SMF   1789968   // [128][n][p]
#define OFF_SBV   1811856   // [128][12]
#define OFF_SSFX  1813392   // [128][12]
#define OFF_GOLDP 1815120   // [2048] per-block gold partials

__device__ __forceinline__ void load12(const float* __restrict__ p, float* r) {
  const float4* p4 = (const float4*)p;
  float4 a = p4[0], b = p4[1], c = p4[2];
  r[0]=a.x; r[1]=a.y; r[2]=a.z; r[3]=a.w;
  r[4]=b.x; r[5]=b.y; r[6]=b.z; r[7]=b.w;
  r[8]=c.x; r[9]=c.y; r[10]=c.z; r[11]=c.w;
}

__device__ __forceinline__ void lds12(const float* p, float* r) {
  const float4* p4 = (const float4*)p;
  float4 a = p4[0], b = p4[1], c = p4[2];
  r[0]=a.x; r[1]=a.y; r[2]=a.z; r[3]=a.w;
  r[4]=b.x; r[5]=b.y; r[6]=b.z; r[7]=b.w;
  r[8]=c.x; r[9]=c.y; r[10]=c.z; r[11]=c.w;
}

__device__ __forceinline__ float tmax12(const float* t) {
  float a = fmaxf(fmaxf(t[0], t[1]), fmaxf(t[2], t[3]));
  float b = fmaxf(fmaxf(t[4], t[5]), fmaxf(t[6], t[7]));
  float c = fmaxf(fmaxf(t[8], t[9]), fmaxf(t[10], t[11]));
  return fmaxf(fmaxf(a, b), c);
}

// ---------------- K1: feats + expfeat + featmax + gold partials -------------
__global__ __launch_bounds__(256) void k_feats(
    const int* __restrict__ sentence, const int* __restrict__ tags,
    const float* __restrict__ emb, const float* __restrict__ W,
    const float* __restrict__ trans, float* __restrict__ ws)
{
  __shared__ float Wl[NTAGS * EMBD];
  __shared__ float gacc;
  for (int i = threadIdx.x; i < NTAGS * EMBD; i += 256) Wl[i] = W[i];
  if (threadIdx.x == 0) gacc = 0.f;
  __syncthreads();

  int grp = threadIdx.x >> 4;
  int g   = threadIdx.x & 15;
  int pos = blockIdx.x * 16 + grp;
  int row = sentence[pos];

  float acc = 0.f;
  if (g < R) {
    const float4* e4 = (const float4*)(emb + (size_t)row * EMBD);
    const float4* w4 = (const float4*)(Wl + g * EMBD);
    #pragma unroll 5
    for (int i = 0; i < EMBD / 4; ++i) {
      float4 a = e4[i]; float4 b = w4[i];
      acc += a.x*b.x + a.y*b.y + a.z*b.z + a.w*b.w;
    }
  }
  float feat = (g < R) ? acc : -3.0e38f;
  float mx = feat;
  #pragma unroll
  for (int off = 1; off < 16; off <<= 1)
    mx = fmaxf(mx, __shfl_xor(mx, off, 16));

  if (g < R) {
    ws[OFF_FEATS + pos * 12 + g] = feat;
    ws[OFF_EXPF  + pos * 12 + g] = __expf(feat - mx);
  }
  if (g == 0) ws[OFF_FMAX + pos] = mx;

  int tg = tags[pos];
  if (g == tg) {
    int prev = (pos == 0) ? T_START : tags[pos - 1];
    float gc = feat + trans[tg * NTAGS + prev];
    if (pos == LSEQ - 1) gc += trans[T_STOP * NTAGS + tg];
    atomicAdd(&gacc, gc);
  }
  __syncthreads();
  if (threadIdx.x == 0) ws[OFF_GOLDP + blockIdx.x] = gacc;
}

// ---------------- K2: chunk transfer matrices + in-block fold1 --------------
// grid 256 = 128 supers x 2 semirings (sem = bid>>7: 0 LSE, 1 viterbi).
// block 256 thr = 16 chunks x 16 cols. Phase A: per-thread 16-step chunk
// scan; chunk mats -> global (PF / PV+PVC) AND LDS. Phase B: threads 0..143
// fold the 16 LDS mats -> super mat (SMF / SMV+SMVT).
// __launch_bounds__(256,1): allow ~200 VGPR, 1 wave/SIMD — no spill.
__global__ __launch_bounds__(256, 1) void k_pass1f(
    const float* __restrict__ trans, float* __restrict__ ws)
{
  __shared__ float Msh[16 * 144];   // 9.2 KB
  __shared__ float Vl[144];

  int tid = threadIdx.x;
  int sem = blockIdx.x >> 7;
  int s   = blockIdx.x & 127;
  int q = tid >> 4;
  int p = tid & 15;
  int c = s * 16 + q;
  int t0 = (c == 0) ? 1 : c * SCH;
  int t1 = c * SCH + SCH;
  bool act = (p < R);

  float Treg[R][R];

  if (sem == 0) {
    // LSE semiring (prob domain with exponent rescaling)
    #pragma unroll
    for (int n = 0; n < R; ++n)
      #pragma unroll
      for (int m = 0; m < R; ++m)
        Treg[n][m] = __expf(trans[n * NTAGS + m]);

    float E[R];
    #pragma unroll
    for (int m = 0; m < R; ++m) E[m] = (m == p) ? 1.f : 0.f;
    int kacc = 0;
    float sfeat = 0.f;

    float ef[R];
    load12(ws + OFF_EXPF + t0 * 12, ef);
    float fm = ws[OFF_FMAX + t0];

    for (int t = t0; t < t1; ++t) {
      float efn[R];
      load12(ws + OFF_EXPF + (t + 1) * 12, efn);   // off-end lands in FMAX: safe
      float fmn = ws[OFF_FMAX + t + 1];            // off-end lands in PF: safe
      sfeat += fm;
      float NE[R];
      #pragma unroll
      for (int n = 0; n < R; ++n) {
        float sv = Treg[n][0] * E[0];
        #pragma unroll
        for (int m = 1; m < R; ++m) sv = fmaf(Treg[n][m], E[m], sv);
        NE[n] = sv * ef[n];
      }
      #pragma unroll
      for (int n = 0; n < R; ++n) E[n] = NE[n];
      if ((t & 7) == 7) {
        float mx = E[0];
        #pragma unroll
        for (int n = 1; n < R; ++n) mx = fmaxf(mx, E[n]);
        if (mx > 0.f) {
          int k = ((__float_as_int(mx) >> 23) & 0xFF) - 127;
          float sc = __int_as_float((127 - k) << 23);
          #pragma unroll
          for (int n = 0; n < R; ++n) E[n] *= sc;
          kacc += k;
        }
      }
      #pragma unroll
      for (int n = 0; n < R; ++n) ef[n] = efn[n];
      fm = fmn;
    }
    if (act) {
      float base = (float)kacc * 0.6931471805599453f + sfeat;
      #pragma unroll
      for (int n = 0; n < R; ++n) {
        float v = (E[n] > 0.f) ? (__logf(E[n]) + base) : -1.0e30f;
        ws[OFF_PF + c * 144 + n * 12 + p] = v;
        Msh[q * 144 + n * 12 + p] = v;
      }
    }
  } else {
    // max-plus semiring
    #pragma unroll
    for (int n = 0; n < R; ++n)
      #pragma unroll
      for (int m = 0; m < R; ++m)
        Treg[n][m] = trans[n * NTAGS + m];

    float V[R];
    #pragma unroll
    for (int m = 0; m < R; ++m) V[m] = (m == p) ? 0.f : -1.0e30f;

    float fr[R];
    load12(ws + OFF_FEATS + t0 * 12, fr);

    for (int t = t0; t < t1; ++t) {
      float frn[R];
      load12(ws + OFF_FEATS + (t + 1) * 12, frn);  // off-end lands in EXPF: safe
      float NV[R];
      #pragma unroll
      for (int n = 0; n < R; ++n) {
        float b = Treg[n][0] + V[0];
        #pragma unroll
        for (int m = 1; m < R; ++m) b = fmaxf(b, Treg[n][m] + V[m]);
        NV[n] = b + fr[n];
      }
      #pragma unroll
      for (int n = 0; n < R; ++n) { V[n] = NV[n]; fr[n] = frn[n]; }
    }
    if (act) {
      #pragma unroll
      for (int n = 0; n < R; ++n) {
        ws[OFF_PV  + c * 144 + n * 12 + p] = V[n];
        ws[OFF_PVC + c * 144 + p * 12 + n] = V[n];
        Msh[q * 144 + n * 12 + p] = V[n];
      }
    }
  }
  __syncthreads();

  // Phase B: fold 16 chunk mats (LDS) -> super mat
  {
    int l = tid;
    bool fa = (l < 144);
    int fn = l / 12;
    int fp = l - fn * 12;
    float V = (fa && fn == fp) ? 0.f : -1.0e30f;

    for (int j = 0; j < 16; ++j) {
      if (fa) Vl[l] = V;
      __syncthreads();
      if (fa) {
        const float* M = Msh + j * 144 + fn * 12;
        if (sem == 1) {
          float best = -3.0e38f;
          #pragma unroll
          for (int m = 0; m < R; ++m)
            best = fmaxf(best, M[m] + Vl[m * 12 + fp]);
          V = best;
        } else {
          float cand[R]; float mx = -3.0e38f;
          #pragma unroll
          for (int m = 0; m < R; ++m) {
            cand[m] = M[m] + Vl[m * 12 + fp];
            mx = fmaxf(mx, cand[m]);
          }
          float sum = 0.f;
          #pragma unroll
          for (int m = 0; m < R; ++m) sum += __expf(cand[m] - mx);
          V = mx + __logf(sum);
        }
      }
      __syncthreads();
    }
    if (fa) {
      if (sem == 1) {
        ws[OFF_SMV  + s * 144 + fn * 12 + fp] = V;
        ws[OFF_SMVT + s * 144 + fp * 12 + fn] = V;
      } else {
        ws[OFF_SMF + s * 144 + fn * 12 + fp] = V;
      }
    }
  }
}

// ---------------- K_midS: LDS-staged serial super scans + gold (2 blocks) ---
// block 0: stage SMV+SMVT into LDS (147KB), wave0 = viterbi fwd (SBV+out[1]),
//          wave1 = viterbi suffix (SSFX). 128 LDS-resident steps each.
// block 1: stage SMF (72KB), wave0 = LSE fwd, wave1 = gold reduce -> out[0].
__global__ __launch_bounds__(256) void k_midS(
    const float* __restrict__ trans, float* __restrict__ ws,
    float* __restrict__ out)
{
  __shared__ float sh[2][NSUP * 144];   // 147456 B
  __shared__ float gold_sh, lse_sh;
  int tid  = threadIdx.x;
  int wid  = tid >> 6;
  int lane = tid & 63;
  int n = lane;
  bool act = (n < R);

  if (blockIdx.x == 0) {
    // stage SMV -> sh[0], SMVT -> sh[1]  (128*36 = 4608 float4 each)
    {
      const float4* a4 = (const float4*)(ws + OFF_SMV);
      const float4* b4 = (const float4*)(ws + OFF_SMVT);
      float4* d0 = (float4*)sh[0];
      float4* d1 = (float4*)sh[1];
      for (int i = tid; i < NSUP * 36; i += 256) { d0[i] = a4[i]; d1[i] = b4[i]; }
    }
    __syncthreads();

    if (wid == 0) {
      // Viterbi forward: SBV[s] = v before applying SMV[s]; then out[1]
      float v = act ? (trans[n * NTAGS + T_START] + ws[OFF_FEATS + n]) : -3.0e38f;
      float row[R], rown[R];
      if (act) lds12(sh[0] + n * 12, row);
      for (int s = 0; s < NSUP; ++s) {
        int nx = (s + 1 < NSUP) ? s + 1 : s;
        if (act) lds12(sh[0] + nx * 144 + n * 12, rown);
        if (act) ws[OFF_SBV + s * 12 + n] = v;
        float vb[R];
        #pragma unroll
        for (int m = 0; m < R; ++m) vb[m] = __shfl(v, m, 16);
        if (act) {
          float t[R];
          #pragma unroll
          for (int m = 0; m < R; ++m) t[m] = row[m] + vb[m];
          v = tmax12(t);
          #pragma unroll
          for (int m = 0; m < R; ++m) row[m] = rown[m];
        }
      }
      float t = act ? (v + trans[T_STOP * NTAGS + n]) : -3.0e38f;
      #pragma unroll
      for (int off = 1; off < 16; off <<= 1)
        t = fmaxf(t, __shfl_xor(t, off, 16));
      if (lane == 0) out[1] = t;
    } else if (wid == 1) {
      // Viterbi suffix: SSFX[s] = u (suffix at exit of super s)
      float u = act ? trans[T_STOP * NTAGS + n] : -3.0e38f;
      if (act) ws[OFF_SSFX + (NSUP - 1) * 12 + n] = u;
      float row[R], rown[R];
      if (act) lds12(sh[1] + (NSUP - 1) * 144 + n * 12, row);
      for (int s = NSUP - 1; s >= 1; --s) {
        int nx = (s >= 2) ? s - 2 : 0;
        if (act) lds12(sh[1] + nx * 144 + n * 12, rown);
        float ub[R];
        #pragma unroll
        for (int m = 0; m < R; ++m) ub[m] = __shfl(u, m, 16);
        if (act) {
          float t[R];
          #pragma unroll
          for (int m = 0; m < R; ++m) t[m] = row[m] + ub[m];
          u = tmax12(t);
          ws[OFF_SSFX + (s - 1) * 12 + n] = u;
          #pragma unroll
          for (int m = 0; m < R; ++m) row[m] = rown[m];
        }
      }
    }
  } else {
    // stage SMF -> sh[0]
    {
      const float4* c4 = (const float4*)(ws + OFF_SMF);
      float4* d0 = (float4*)sh[0];
      for (int i = tid; i < NSUP * 36; i += 256) d0[i] = c4[i];
    }
    __syncthreads();

    if (wid == 0) {
      // LSE forward -> lse_sh
      float w = act ? (trans[n * NTAGS + T_START] + ws[OFF_FEATS + n]) : -3.0e38f;
      float row[R], rown[R];
      if (act) lds12(sh[0] + n * 12, row);
      for (int s = 0; s < NSUP; ++s) {
        int nx = (s + 1 < NSUP) ? s + 1 : s;
        if (act) lds12(sh[0] + nx * 144 + n * 12, rown);
        float wb[R];
        #pragma unroll
        for (int m = 0; m < R; ++m) wb[m] = __shfl(w, m, 16);
        if (act) {
          float t[R];
          #pragma unroll
          for (int m = 0; m < R; ++m) t[m] = row[m] + wb[m];
          float mx = tmax12(t);
          float sum = 0.f;
          #pragma unroll
          for (int m = 0; m < R; ++m) sum += __expf(t[m] - mx);
          w = mx + __logf(sum);
          #pragma unroll
          for (int m = 0; m < R; ++m) row[m] = rown[m];
        }
      }
      float t = act ? (w + trans[T_STOP * NTAGS + n]) : -3.0e38f;
      float mx = t;
      #pragma unroll
      for (int off = 1; off < 16; off <<= 1)
        mx = fmaxf(mx, __shfl_xor(mx, off, 16));
      float e = act ? __expf(t - mx) : 0.f;
      #pragma unroll
      for (int off = 1; off < 16; off <<= 1)
        e += __shfl_xor(e, off, 16);
      if (lane == 0) lse_sh = mx + __logf(e);
    } else if (wid == 1) {
      // gold reduce over 2048 partials
      float sg = 0.f;
      for (int i = lane; i < CCH; i += 64) sg += ws[OFF_GOLDP + i];
      #pragma unroll
      for (int off = 1; off < 64; off <<= 1) sg += __shfl_xor(sg, off);
      if (lane == 0) gold_sh = sg;
    }
    __syncthreads();
    if (tid == 0) out[0] = lse_sh - gold_sh;
  }
}

// ---------------- K_expBdec: per-super expandB scans + decode ---------------
// 128 blocks x 256 thr. Phase A: wave0 lanes 0-15 compute BV for the super's
// 16 chunks (LDS); wave1 lanes 0-15 compute SFX. Phase B: decode 16 chunks
// x 16 lanes. No BV/SFX global round-trip.
__global__ __launch_bounds__(256) void k_expBdec(
    const float* __restrict__ trans, const float* __restrict__ ws,
    float* __restrict__ out)
{
  __shared__ float bv_sh[SCH][12];
  __shared__ float sfx_sh[SCH][12];
  __shared__ float Vdec[SCH][16];
  __shared__ unsigned char bpd[SCH][SCH][16];

  int tid = threadIdx.x;
  int s   = blockIdx.x;

  if (tid < 16) {
    // dir0: BV scan over PV mats
    int g = tid; bool act = (g < R);
    float x = -3.0e38f;
    if (act) { x = ws[OFF_SBV + s * 12 + g]; bv_sh[0][g] = x; }
    float row[R], rown[R];
    if (act) load12(ws + OFF_PV + (s * 16) * 144 + g * 12, row);
    for (int j = 0; j < 15; ++j) {
      if (act) load12(ws + OFF_PV + (s * 16 + j + 1) * 144 + g * 12, rown);
      float v[R];
      lds12(bv_sh[j], v);
      if (act) {
        float nx = row[0] + v[0];
        #pragma unroll
        for (int m = 1; m < R; ++m) nx = fmaxf(nx, row[m] + v[m]);
        bv_sh[j + 1][g] = nx;
        #pragma unroll
        for (int m = 0; m < R; ++m) row[m] = rown[m];
      }
    }
  } else if (tid >= 64 && tid < 80) {
    // dir1: SFX scan over PVC mats
    int g = tid - 64; bool act = (g < R);
    float x = -3.0e38f;
    if (act) { x = ws[OFF_SSFX + s * 12 + g]; sfx_sh[SCH - 1][g] = x; }
    float row[R], rown[R];
    if (act) load12(ws + OFF_PVC + (s * 16 + 15) * 144 + g * 12, row);
    for (int j = 15; j >= 1; --j) {
      if (act) load12(ws + OFF_PVC + (s * 16 + j - 1) * 144 + g * 12, rown);
      float v[R];
      lds12(sfx_sh[j], v);
      if (act) {
        float nx = row[0] + v[0];
        #pragma unroll
        for (int m = 1; m < R; ++m) nx = fmaxf(nx, row[m] + v[m]);
        sfx_sh[j - 1][g] = nx;
        #pragma unroll
        for (int m = 0; m < R; ++m) row[m] = rown[m];
      }
    }
  }
  __syncthreads();

  // decode: 16 chunks x 16 lanes
  {
    int q = tid >> 4;
    int g = tid & 15;
    int c = s * 16 + q;
    int t0 = (c == 0) ? 1 : c * SCH;
    int t1 = c * SCH + SCH;
    bool act = (g < R);

    float treg[R];
    #pragma unroll
    for (int m = 0; m < R; ++m) treg[m] = act ? trans[g * NTAGS + m] : 0.f;

    float fv = act ? bv_sh[q][g] : -3.0e38f;
    Vdec[q][g] = fv;
    float fc = ws[OFF_FEATS + t0 * 12 + g];

    for (int t = t0; t < t1; ++t) {
      float fn = ws[OFF_FEATS + (t + 1) * 12 + g];   // off-end: EXPF, unused
      float v[R];
      lds12(Vdec[q], v);
      float best = -3.0e38f; int bi = 0;
      #pragma unroll
      for (int m = 0; m < R; ++m) {
        float cand = treg[m] + v[m];
        if (cand > best) { best = cand; bi = m; }
      }
      float nfv = best + fc;
      if (act) {
        bpd[q][t - t0][g] = (unsigned char)bi;
        Vdec[q][g] = nfv;
      }
      fc = fn;
    }

    Vdec[q][g] = act ? (Vdec[q][g] + sfx_sh[q][g]) : -3.0e38f;

    if (g == 0) {
      float best = Vdec[q][0]; int idx = 0;
      #pragma unroll
      for (int m = 1; m < R; ++m) {
        float v = Vdec[q][m];
        if (v > best) { best = v; idx = m; }
      }
      int cur = idx;
      int len = t1 - t0;
      out[2 + t0 + len - 1] = (float)cur;
      for (int tt = len - 1; tt >= 1; --tt) {
        cur = bpd[q][tt][cur];
        out[2 + t0 + tt - 1] = (float)cur;
      }
      if (c == 0) {
        cur = bpd[q][0][cur];
        out[2 + 0] = (float)cur;
      }
    }
  }
}

extern "C" void kernel_launch(void* const* d_in, const int* in_sizes, int n_in,
                              void* d_out, int out_size, void* d_ws, size_t ws_size,
                              hipStream_t stream) {
  (void)in_sizes; (void)n_in; (void)out_size; (void)ws_size;
  const int*   sentence = (const int*)d_in[0];
  const int*   tags     = (const int*)d_in[1];
  const float* emb      = (const float*)d_in[2];
  const float* W        = (const float*)d_in[3];
  const float* trans    = (const float*)d_in[4];
  float* ws  = (float*)d_ws;
  float* out = (float*)d_out;

  k_feats<<<LSEQ / 16, 256, 0, stream>>>(sentence, tags, emb, W, trans, ws);
  k_pass1f<<<NSUP * 2, 256, 0, stream>>>(trans, ws);
  k_midS<<<2, 256, 0, stream>>>(trans, ws, out);
  k_expBdec<<<NSUP, 256, 0, stream>>>(trans, ws, out);
}